// Round 3
// baseline (19658.151 us; speedup 1.0000x reference)
//
#include <hip/hip_runtime.h>
#include <stdint.h>

// ---------------------------------------------------------------------------
// ComplexApproximateBNN, round 3: single persistent cooperative kernel for
// all 128 timesteps. R2's per-phase GEMM partitioning retained:
//   C[64,2048] = act(concat(A1,A2)[64,4096] @ W[2048,4096]^T + b)
//   256 WGs = 128 n-tiles (16 cols) x 2 m-halves (32 rows); K split over the
//   4 waves (waves 0,1 -> A1, waves 2,3 -> A2); LDS reduce; fused bias/act.
// l2norm fused via per-row sumsq (atomicAdd) + A2-partial scaling (exact).
// Grid barrier: sense-reversing, agent-scope atomics + __threadfence
// (release: all WG stores are in L2 by s_barrier's vmcnt(0); thread0's agent
// fence writes back L2; acquire side invalidates). 4 barriers/step.
// y_t (out layer) runs barrier-free on WGs 224..255 during step t+1's
// h1-phase (h4 still intact until the next h4-phase).
// ---------------------------------------------------------------------------

typedef __bf16 bf16;
typedef __attribute__((ext_vector_type(8))) __bf16 bf16x8;
typedef __attribute__((ext_vector_type(4))) float f32x4;

#define BATCH 64
#define TSTEPS 128
#define INDIM 512
#define XDIM 2048
#define OUTDIM 256
#define NWG 256

__device__ __forceinline__ float apply_act(float h, int id) {
  switch (id) {
    case 0: return fmaxf(h, 0.0f);                       // relu
    case 1: return 1.0f / (1.0f + __expf(-h));           // sigmoid
    case 2: return tanhf(h);                             // tanh
    case 3: return h >= 0.0f ? h : 0.1f * h;             // leaky 0.1
    default: {                                           // selu
      const float sc = 1.0507009873554805f;
      const float al = 1.6732632423543772f;
      return h > 0.0f ? sc * h : sc * al * (__expf(h) - 1.0f);
    }
  }
}

// grid-wide barrier; target = running barrier count (monotone)
__device__ __forceinline__ void gbar(uint32_t* cnt, uint32_t* ep, uint32_t target) {
  __syncthreads();  // implies vmcnt(0): this WG's stores have reached L2
  if (threadIdx.x == 0) {
    __threadfence();  // agent release: write back L2 (cross-XCD visibility)
    uint32_t prev = __hip_atomic_fetch_add(cnt, 1u, __ATOMIC_ACQ_REL, __HIP_MEMORY_SCOPE_AGENT);
    if (prev == NWG - 1) {
      __hip_atomic_store(cnt, 0u, __ATOMIC_RELAXED, __HIP_MEMORY_SCOPE_AGENT);
      __hip_atomic_fetch_add(ep, 1u, __ATOMIC_RELEASE, __HIP_MEMORY_SCOPE_AGENT);
    } else {
      while (__hip_atomic_load(ep, __ATOMIC_RELAXED, __HIP_MEMORY_SCOPE_AGENT) < target) {
        __builtin_amdgcn_s_sleep(2);
      }
    }
    __threadfence();  // agent acquire: invalidate stale cached lines
  }
  __syncthreads();
}

// one hidden-layer phase for this WG's (n_tile, m_half) tile
template <bool SCALE_A2, bool EMIT_SS>
__device__ __forceinline__ void hphase(
    int n_tile, int m_half,
    const bf16* __restrict__ A1, const bf16* __restrict__ A2,
    const bf16* __restrict__ W, const float* __restrict__ bias,
    const int* __restrict__ acts, const float* __restrict__ ss_in,
    float* __restrict__ ss_out, bf16* __restrict__ outb,
    float red[4][32][17]) {
  const int tid = threadIdx.x;
  const int lane = tid & 63;
  const int w = tid >> 6;
  const int l15 = lane & 15;
  const int kb8 = (lane >> 4) * 8;
  const int nblk = n_tile * 16;
  const int mrow = m_half * 32;

  const bf16* As = (w >= 2) ? A2 : A1;
  const int koff = (w & 1) * 1024;
  const int wk = (w >= 2 ? 2048 : 0) + koff;

  const bf16* ap0 = As + (size_t)(mrow + l15) * 2048 + koff + kb8;
  const bf16* ap1 = ap0 + 16 * 2048;
  const bf16* bpw = W + (size_t)(nblk + l15) * 4096 + wk + kb8;

  f32x4 acc0 = {0.f, 0.f, 0.f, 0.f};
  f32x4 acc1 = {0.f, 0.f, 0.f, 0.f};
#pragma unroll 4
  for (int k = 0; k < 1024; k += 32) {
    bf16x8 a0 = *(const bf16x8*)(ap0 + k);
    bf16x8 a1 = *(const bf16x8*)(ap1 + k);
    bf16x8 b  = *(const bf16x8*)(bpw + k);
    acc0 = __builtin_amdgcn_mfma_f32_16x16x32_bf16(a0, b, acc0, 0, 0, 0);
    acc1 = __builtin_amdgcn_mfma_f32_16x16x32_bf16(a1, b, acc1, 0, 0, 0);
  }

  const int q4 = lane >> 4;
#pragma unroll
  for (int r = 0; r < 4; r++) red[w][q4 * 4 + r][l15] = acc0[r];
#pragma unroll
  for (int r = 0; r < 4; r++) red[w][16 + q4 * 4 + r][l15] = acc1[r];
  __syncthreads();

  const int row = tid >> 3;
  const int c0 = (tid & 7) * 2;
  const int rg = mrow + row;
  float scale = 1.0f;
  if (SCALE_A2) scale = 1.0f / fmaxf(sqrtf(ss_in[rg]), 1e-12f);

  float v[2];
#pragma unroll
  for (int j = 0; j < 2; j++) {
    int c = c0 + j;
    float lo = red[0][row][c] + red[1][row][c];
    float hi = red[2][row][c] + red[3][row][c];
    float pre = (SCALE_A2 ? (lo + scale * hi) : (lo + hi)) + bias[nblk + c];
    v[j] = apply_act(pre, acts[nblk + c]);
  }
  if (EMIT_SS) {
    float ss = v[0] * v[0] + v[1] * v[1];
    ss += __shfl_xor(ss, 1);
    ss += __shfl_xor(ss, 2);
    ss += __shfl_xor(ss, 4);
    if ((tid & 7) == 0) atomicAdd(ss_out + rg, ss);
  }
  union { bf16 b2[2]; uint32_t u; } pk;
  pk.b2[0] = (bf16)v[0];
  pk.b2[1] = (bf16)v[1];
  *(uint32_t*)(outb + (size_t)rg * XDIM + nblk + c0) = pk.u;
}

// output layer y_t = act(h4 @ Wout^T + bout), 32 WGs, idx in [0,32)
__device__ void yphase(int idx, const bf16* __restrict__ h4,
                       const bf16* __restrict__ Wout,
                       const float* __restrict__ bout,
                       const int* __restrict__ oact,
                       float* __restrict__ out, int t,
                       float red[4][32][17]) {
  __syncthreads();  // protect red[] against preceding hphase epilogue reads
  const int tid = threadIdx.x;
  const int lane = tid & 63;
  const int w = tid >> 6;
  const int l15 = lane & 15;
  const int kb8 = (lane >> 4) * 8;
  const int nblk = (idx & 15) * 16;
  const int mrow = (idx >> 4) * 32;
  const int koff = w * 512;

  const bf16* ap0 = h4 + (size_t)(mrow + l15) * 2048 + koff + kb8;
  const bf16* ap1 = ap0 + 16 * 2048;
  const bf16* bpw = Wout + (size_t)(nblk + l15) * 2048 + koff + kb8;

  f32x4 acc0 = {0.f, 0.f, 0.f, 0.f};
  f32x4 acc1 = {0.f, 0.f, 0.f, 0.f};
#pragma unroll 4
  for (int k = 0; k < 512; k += 32) {
    bf16x8 a0 = *(const bf16x8*)(ap0 + k);
    bf16x8 a1 = *(const bf16x8*)(ap1 + k);
    bf16x8 b  = *(const bf16x8*)(bpw + k);
    acc0 = __builtin_amdgcn_mfma_f32_16x16x32_bf16(a0, b, acc0, 0, 0, 0);
    acc1 = __builtin_amdgcn_mfma_f32_16x16x32_bf16(a1, b, acc1, 0, 0, 0);
  }
  const int q4 = lane >> 4;
#pragma unroll
  for (int r = 0; r < 4; r++) red[w][q4 * 4 + r][l15] = acc0[r];
#pragma unroll
  for (int r = 0; r < 4; r++) red[w][16 + q4 * 4 + r][l15] = acc1[r];
  __syncthreads();

  const int row = tid >> 3;
  const int c0 = (tid & 7) * 2;
  const int rg = mrow + row;
  float v[2];
#pragma unroll
  for (int j = 0; j < 2; j++) {
    int c = c0 + j;
    float pre = red[0][row][c] + red[1][row][c] + red[2][row][c] +
                red[3][row][c] + bout[nblk + c];
    v[j] = apply_act(pre, oact[nblk + c]);
  }
  *(float2*)(out + ((size_t)rg * TSTEPS + t) * OUTDIM + nblk + c0) =
      make_float2(v[0], v[1]);
}

struct Params {
  const bf16* h0;
  const bf16* whb;
  const float* b_h;
  const int* act_ids;
  const bf16* woutb;
  const float* b_out;
  const int* out_act;
  bf16 *h1, *h2a, *h2b, *h3, *h4;
  float *ss_li, *ss_bp, *out;
  uint32_t *cnt, *ep;
};

__global__ __launch_bounds__(256) void bnn_persistent(Params p) {
  __shared__ float red[4][32][17];
  const int wg = blockIdx.x;
  const int n_tile = wg & 127;
  const int m_half = wg >> 7;
  const size_t wstr = (size_t)XDIM * 2 * XDIM;
  uint32_t bt = 0;

  for (int t = 0; t < TSTEPS; t++) {
    const bf16* h0t = p.h0 + (size_t)t * BATCH * XDIM;
    bf16* h2n = (t & 1) ? p.h2b : p.h2a;
    bf16* h2o = (t & 1) ? p.h2a : p.h2b;

    // phase A: h1 = act([h0_t, norm(h4)] @ W0^T + b0); WGs 224+ also y_{t-1}
    hphase<true, false>(n_tile, m_half, h0t, p.h4, p.whb, p.b_h,
                        p.act_ids + XDIM, p.ss_bp + t * BATCH, nullptr, p.h1, red);
    if (wg >= 224 && t > 0)
      yphase(wg - 224, p.h4, p.woutb, p.b_out, p.out_act, p.out, t - 1, red);
    gbar(p.cnt, p.ep, ++bt);

    // phase B: h2 = act([h1, norm(h2_old)] @ W1^T + b1); emit ss_li[t+1]
    hphase<true, true>(n_tile, m_half, p.h1, h2o, p.whb + wstr, p.b_h + XDIM,
                       p.act_ids + 2 * XDIM, p.ss_li + t * BATCH,
                       p.ss_li + (t + 1) * BATCH, h2n, red);
    gbar(p.cnt, p.ep, ++bt);

    // phase C: h3 = act([h2, h1] @ W2^T + b2)
    hphase<false, false>(n_tile, m_half, h2n, p.h1, p.whb + 2 * wstr,
                         p.b_h + 2 * XDIM, p.act_ids + 3 * XDIM,
                         nullptr, nullptr, p.h3, red);
    gbar(p.cnt, p.ep, ++bt);

    // phase D: h4 = act([h3, h2] @ W3^T + b3); emit ss_bp[t+1]
    hphase<false, true>(n_tile, m_half, p.h3, h2n, p.whb + 3 * wstr,
                        p.b_h + 3 * XDIM, p.act_ids + 4 * XDIM, nullptr,
                        p.ss_bp + (t + 1) * BATCH, p.h4, red);
    gbar(p.cnt, p.ep, ++bt);
  }
  // tail: y_127
  if (wg >= 224)
    yphase(wg - 224, p.h4, p.woutb, p.b_out, p.out_act, p.out, TSTEPS - 1, red);
}

// h0 precompute: [8192,512]@[512->2048], rows r=b*128+t remapped to [t][b][n]
__global__ __launch_bounds__(256) void h0_gemm(
    const bf16* __restrict__ A, const bf16* __restrict__ W,
    const float* __restrict__ bias, const int* __restrict__ acts,
    bf16* __restrict__ outp) {
  const int tid = threadIdx.x;
  const int lane = tid & 63;
  const int wv = tid >> 6;
  const int wm = (wv & 1) * 32;
  const int wn = (wv >> 1) * 64;
  const int nblk = blockIdx.x * 128;
  const int mblk = blockIdx.y * 64;
  const int l15 = lane & 15;
  const int kb8 = (lane >> 4) * 8;

  f32x4 acc[2][4];
  const f32x4 zero = {0.f, 0.f, 0.f, 0.f};
#pragma unroll
  for (int i = 0; i < 2; i++)
#pragma unroll
    for (int j = 0; j < 4; j++) acc[i][j] = zero;

  for (int kt = 0; kt < INDIM; kt += 32) {
    bf16x8 a[2], b[4];
#pragma unroll
    for (int mt = 0; mt < 2; mt++) {
      int m = mblk + wm + mt * 16 + l15;
      a[mt] = *(const bf16x8*)(A + (size_t)m * INDIM + kt + kb8);
    }
#pragma unroll
    for (int nt = 0; nt < 4; nt++) {
      int n = nblk + wn + nt * 16 + l15;
      b[nt] = *(const bf16x8*)(W + (size_t)n * INDIM + kt + kb8);
    }
#pragma unroll
    for (int mt = 0; mt < 2; mt++)
#pragma unroll
      for (int nt = 0; nt < 4; nt++)
        acc[mt][nt] = __builtin_amdgcn_mfma_f32_16x16x32_bf16(a[mt], b[nt], acc[mt][nt], 0, 0, 0);
  }

#pragma unroll
  for (int mt = 0; mt < 2; mt++) {
#pragma unroll
    for (int nt = 0; nt < 4; nt++) {
      int n = nblk + wn + nt * 16 + l15;
      float bv = bias[n];
      int aid = acts[n];
#pragma unroll
      for (int rr = 0; rr < 4; rr++) {
        int m = wm + mt * 16 + (lane >> 4) * 4 + rr;
        float v = apply_act(acc[mt][nt][rr] + bv, aid);
        int rowg = mblk + m;  // = b*128 + t
        int bb = rowg >> 7;
        int tt = rowg & 127;
        outp[((size_t)tt * BATCH + bb) * XDIM + n] = (bf16)v;
      }
    }
  }
}

__global__ __launch_bounds__(256) void cvt_bf16(
    const float* __restrict__ in, bf16* __restrict__ out, int n4) {
  int i = blockIdx.x * 256 + threadIdx.x;
  if (i < n4) {
    float4 v = ((const float4*)in)[i];
    union { bf16 b[4]; unsigned long long u; } pk;
    pk.b[0] = (bf16)v.x;
    pk.b[1] = (bf16)v.y;
    pk.b[2] = (bf16)v.z;
    pk.b[3] = (bf16)v.w;
    ((unsigned long long*)out)[i] = pk.u;
  }
}

__global__ __launch_bounds__(256) void zero32(uint32_t* __restrict__ p, int n) {
  int i = blockIdx.x * 256 + threadIdx.x;
  if (i < n) p[i] = 0u;
}

extern "C" void kernel_launch(void* const* d_in, const int* in_sizes, int n_in,
                              void* d_out, int out_size, void* d_ws, size_t ws_size,
                              hipStream_t stream) {
  const float* x     = (const float*)d_in[0];   // [64,128,512]
  const float* W_in  = (const float*)d_in[1];   // [2048,512]
  const float* b_in  = (const float*)d_in[2];   // [2048]
  const float* W_h   = (const float*)d_in[3];   // [4,2048,4096]
  const float* b_h   = (const float*)d_in[4];   // [4,2048]
  const float* W_out = (const float*)d_in[5];   // [256,2048]
  const float* b_out = (const float*)d_in[6];   // [256]
  const int* act_ids = (const int*)d_in[7];     // [5,2048]
  const int* out_act = (const int*)d_in[8];     // [256]
  float* out = (float*)d_out;                   // [64,128,256]

  char* w = (char*)d_ws;
  bf16* xbf   = (bf16*)w; w += (size_t)BATCH * TSTEPS * INDIM * 2;   // 8 MB
  bf16* winb  = (bf16*)w; w += (size_t)XDIM * INDIM * 2;             // 2 MB
  bf16* whb   = (bf16*)w; w += (size_t)4 * XDIM * (2 * XDIM) * 2;    // 64 MB
  bf16* woutb = (bf16*)w; w += (size_t)OUTDIM * XDIM * 2;            // 1 MB
  bf16* h0    = (bf16*)w; w += (size_t)TSTEPS * BATCH * XDIM * 2;    // 32 MB
  bf16* h1    = (bf16*)w; w += (size_t)BATCH * XDIM * 2;
  bf16* h3    = (bf16*)w; w += (size_t)BATCH * XDIM * 2;
  // ---- zero region ----
  char* zstart = w;
  bf16* h2a   = (bf16*)w; w += (size_t)BATCH * XDIM * 2;
  bf16* h2b   = (bf16*)w; w += (size_t)BATCH * XDIM * 2;
  bf16* h4    = (bf16*)w; w += (size_t)BATCH * XDIM * 2;
  float* ss_li = (float*)w; w += (size_t)(TSTEPS + 1) * BATCH * 4;
  float* ss_bp = (float*)w; w += (size_t)(TSTEPS + 1) * BATCH * 4;
  uint32_t* barv = (uint32_t*)w; w += 256;  // [cnt, epoch]
  int zero_u32 = (int)((w - zstart) / 4);

  cvt_bf16<<<4096, 256, 0, stream>>>(x, xbf, (BATCH * TSTEPS * INDIM) / 4);
  cvt_bf16<<<1024, 256, 0, stream>>>(W_in, winb, (XDIM * INDIM) / 4);
  cvt_bf16<<<32768, 256, 0, stream>>>(W_h, whb, (4 * XDIM * 2 * XDIM) / 4);
  cvt_bf16<<<512, 256, 0, stream>>>(W_out, woutb, (OUTDIM * XDIM) / 4);
  zero32<<<(zero_u32 + 255) / 256, 256, 0, stream>>>((uint32_t*)zstart, zero_u32);
  h0_gemm<<<dim3(16, 128), 256, 0, stream>>>(xbf, winb, b_in, act_ids, h0);

  Params P;
  P.h0 = h0; P.whb = whb; P.b_h = b_h; P.act_ids = act_ids;
  P.woutb = woutb; P.b_out = b_out; P.out_act = out_act;
  P.h1 = h1; P.h2a = h2a; P.h2b = h2b; P.h3 = h3; P.h4 = h4;
  P.ss_li = ss_li; P.ss_bp = ss_bp; P.out = out;
  P.cnt = barv; P.ep = barv + 1;

  void* kargs[] = {&P};
  hipLaunchCooperativeKernel((const void*)bnn_persistent, dim3(NWG), dim3(256),
                             kargs, 0, stream);
}

// Round 4
// 8867.365 us; speedup vs baseline: 2.2169x; 2.2169x over previous
//
#include <hip/hip_runtime.h>
#include <stdint.h>

// ---------------------------------------------------------------------------
// ComplexApproximateBNN, round 4. Multi-dispatch (R2 structure), upgraded:
//  - step GEMM: 512-thread WGs (8 waves), K split 8 ways (512/wave), full
//    k-loop unroll -> ~2x waves/CU and ~4x deeper load pipeline vs R2.
//  - y output layer batched: h4_t stored to rotating slots (overlaid on dead
//    h0 slices), single [8192,2048] GEMM at the end (-128 dispatches).
//  - l2norm fused: producers emit per-row sumsq (atomicAdd), consumers scale
//    the A2 partial (waves 4..7) by rsqrt in the epilogue (exact).
// 4 dispatches per step, 128 steps.
// ---------------------------------------------------------------------------

typedef __bf16 bf16;
typedef __attribute__((ext_vector_type(8))) __bf16 bf16x8;
typedef __attribute__((ext_vector_type(4))) float f32x4;

#define BATCH 64
#define TSTEPS 128
#define INDIM 512
#define XDIM 2048
#define OUTDIM 256
#define SLOTE ((size_t)BATCH * XDIM)  // elements per [b][2048] slot

__device__ __forceinline__ float apply_act(float h, int id) {
  switch (id) {
    case 0: return fmaxf(h, 0.0f);                       // relu
    case 1: return 1.0f / (1.0f + __expf(-h));           // sigmoid
    case 2: return tanhf(h);                             // tanh
    case 3: return h >= 0.0f ? h : 0.1f * h;             // leaky 0.1
    default: {                                           // selu
      const float sc = 1.0507009873554805f;
      const float al = 1.6732632423543772f;
      return h > 0.0f ? sc * h : sc * al * (__expf(h) - 1.0f);
    }
  }
}

// C[64,2048] = act(concat(A1,A2)[64,4096] @ W[2048,4096]^T + b)
// grid (128 n-tiles, 2 m-halves); 8 waves: w<4 -> A1, w>=4 -> A2, k=512 each.
template <bool SCALE_A2, bool EMIT_SS>
__global__ __launch_bounds__(512, 2) void step_gemm8(
    const bf16* __restrict__ A1, const bf16* __restrict__ A2,
    const bf16* __restrict__ W, const float* __restrict__ bias,
    const int* __restrict__ acts, const float* __restrict__ ss_in,
    float* __restrict__ ss_out, bf16* __restrict__ outb) {
  const int tid = threadIdx.x;
  const int lane = tid & 63;
  const int w = tid >> 6;        // 0..7
  const int l15 = lane & 15;
  const int kb8 = (lane >> 4) * 8;
  const int nblk = blockIdx.x * 16;
  const int mrow = blockIdx.y * 32;

  const bf16* As = (w >= 4) ? A2 : A1;
  const int koff = (w & 3) * 512;   // offset within source
  const int wk = w * 512;           // global k for W

  const bf16* ap0 = As + (size_t)(mrow + l15) * 2048 + koff + kb8;
  const bf16* ap1 = ap0 + 16 * 2048;
  const bf16* bpw = W + (size_t)(nblk + l15) * 4096 + wk + kb8;

  f32x4 acc0 = {0.f, 0.f, 0.f, 0.f};
  f32x4 acc1 = {0.f, 0.f, 0.f, 0.f};
#pragma unroll
  for (int k = 0; k < 512; k += 32) {
    bf16x8 a0 = *(const bf16x8*)(ap0 + k);
    bf16x8 a1 = *(const bf16x8*)(ap1 + k);
    bf16x8 b  = *(const bf16x8*)(bpw + k);
    acc0 = __builtin_amdgcn_mfma_f32_16x16x32_bf16(a0, b, acc0, 0, 0, 0);
    acc1 = __builtin_amdgcn_mfma_f32_16x16x32_bf16(a1, b, acc1, 0, 0, 0);
  }

  __shared__ float red[8][32][17];
  const int q4 = lane >> 4;
#pragma unroll
  for (int r = 0; r < 4; r++) red[w][q4 * 4 + r][l15] = acc0[r];
#pragma unroll
  for (int r = 0; r < 4; r++) red[w][16 + q4 * 4 + r][l15] = acc1[r];
  __syncthreads();

  if (tid < 256) {
    const int row = tid >> 3;      // 0..31
    const int c0 = (tid & 7) * 2;  // even col
    const int rg = mrow + row;

    float scale = 1.0f;
    if (SCALE_A2) scale = 1.0f / fmaxf(sqrtf(ss_in[rg]), 1e-12f);

    float v[2];
#pragma unroll
    for (int j = 0; j < 2; j++) {
      int c = c0 + j;
      float lo = red[0][row][c] + red[1][row][c] + red[2][row][c] + red[3][row][c];
      float hi = red[4][row][c] + red[5][row][c] + red[6][row][c] + red[7][row][c];
      float pre = (SCALE_A2 ? (lo + scale * hi) : (lo + hi)) + bias[nblk + c];
      v[j] = apply_act(pre, acts[nblk + c]);
    }
    if (EMIT_SS) {
      float ss = v[0] * v[0] + v[1] * v[1];
      ss += __shfl_xor(ss, 1);
      ss += __shfl_xor(ss, 2);
      ss += __shfl_xor(ss, 4);
      if ((tid & 7) == 0) atomicAdd(ss_out + rg, ss);
    }
    union { bf16 b2[2]; uint32_t u; } pk;
    pk.b2[0] = (bf16)v[0];
    pk.b2[1] = (bf16)v[1];
    *(uint32_t*)(outb + (size_t)rg * XDIM + nblk + c0) = pk.u;
  }
}

// h0 precompute: [8192,512]@[512->2048], rows r=b*128+t remapped to [t][b][n]
__global__ __launch_bounds__(256) void h0_gemm(
    const bf16* __restrict__ A, const bf16* __restrict__ W,
    const float* __restrict__ bias, const int* __restrict__ acts,
    bf16* __restrict__ outp) {
  const int tid = threadIdx.x;
  const int lane = tid & 63;
  const int wv = tid >> 6;
  const int wm = (wv & 1) * 32;
  const int wn = (wv >> 1) * 64;
  const int nblk = blockIdx.x * 128;
  const int mblk = blockIdx.y * 64;
  const int l15 = lane & 15;
  const int kb8 = (lane >> 4) * 8;

  f32x4 acc[2][4];
  const f32x4 zero = {0.f, 0.f, 0.f, 0.f};
#pragma unroll
  for (int i = 0; i < 2; i++)
#pragma unroll
    for (int j = 0; j < 4; j++) acc[i][j] = zero;

  for (int kt = 0; kt < INDIM; kt += 32) {
    bf16x8 a[2], b[4];
#pragma unroll
    for (int mt = 0; mt < 2; mt++) {
      int m = mblk + wm + mt * 16 + l15;
      a[mt] = *(const bf16x8*)(A + (size_t)m * INDIM + kt + kb8);
    }
#pragma unroll
    for (int nt = 0; nt < 4; nt++) {
      int n = nblk + wn + nt * 16 + l15;
      b[nt] = *(const bf16x8*)(W + (size_t)n * INDIM + kt + kb8);
    }
#pragma unroll
    for (int mt = 0; mt < 2; mt++)
#pragma unroll
      for (int nt = 0; nt < 4; nt++)
        acc[mt][nt] = __builtin_amdgcn_mfma_f32_16x16x32_bf16(a[mt], b[nt], acc[mt][nt], 0, 0, 0);
  }

#pragma unroll
  for (int mt = 0; mt < 2; mt++) {
#pragma unroll
    for (int nt = 0; nt < 4; nt++) {
      int n = nblk + wn + nt * 16 + l15;
      float bv = bias[n];
      int aid = acts[n];
#pragma unroll
      for (int rr = 0; rr < 4; rr++) {
        int m = wm + mt * 16 + (lane >> 4) * 4 + rr;
        float v = apply_act(acc[mt][nt][rr] + bv, aid);
        int rowg = mblk + m;  // = b*128 + t
        int bb = rowg >> 7;
        int tt = rowg & 127;
        outp[((size_t)tt * BATCH + bb) * XDIM + n] = (bf16)v;
      }
    }
  }
}

// batched output layer: for each t, y_t = act(h4slot(t+1) @ Wout^T + bout).
// grid (2 n-tiles of 128, 128 t-slots). slot s<2 -> extra, else h0[s-2].
__global__ __launch_bounds__(256) void ybat_gemm(
    const bf16* __restrict__ extra, const bf16* __restrict__ h0,
    const bf16* __restrict__ Wout, const float* __restrict__ bout,
    const int* __restrict__ oact, float* __restrict__ out) {
  const int t = blockIdx.y;
  const int s = t + 1;
  const bf16* A = (s < 2) ? (extra + (size_t)s * SLOTE)
                          : (h0 + (size_t)(s - 2) * SLOTE);
  const int tid = threadIdx.x;
  const int lane = tid & 63;
  const int wv = tid >> 6;
  const int wm = (wv & 1) * 32;
  const int wn = (wv >> 1) * 64;
  const int nblk = blockIdx.x * 128;
  const int l15 = lane & 15;
  const int kb8 = (lane >> 4) * 8;

  f32x4 acc[2][4];
  const f32x4 zero = {0.f, 0.f, 0.f, 0.f};
#pragma unroll
  for (int i = 0; i < 2; i++)
#pragma unroll
    for (int j = 0; j < 4; j++) acc[i][j] = zero;

  for (int kt = 0; kt < XDIM; kt += 32) {
    bf16x8 a[2], b[4];
#pragma unroll
    for (int mt = 0; mt < 2; mt++) {
      int m = wm + mt * 16 + l15;
      a[mt] = *(const bf16x8*)(A + (size_t)m * XDIM + kt + kb8);
    }
#pragma unroll
    for (int nt = 0; nt < 4; nt++) {
      int n = nblk + wn + nt * 16 + l15;
      b[nt] = *(const bf16x8*)(Wout + (size_t)n * XDIM + kt + kb8);
    }
#pragma unroll
    for (int mt = 0; mt < 2; mt++)
#pragma unroll
      for (int nt = 0; nt < 4; nt++)
        acc[mt][nt] = __builtin_amdgcn_mfma_f32_16x16x32_bf16(a[mt], b[nt], acc[mt][nt], 0, 0, 0);
  }

#pragma unroll
  for (int mt = 0; mt < 2; mt++) {
#pragma unroll
    for (int nt = 0; nt < 4; nt++) {
      int n = nblk + wn + nt * 16 + l15;
      float bv = bout[n];
      int aid = oact[n];
#pragma unroll
      for (int rr = 0; rr < 4; rr++) {
        int b = wm + mt * 16 + (lane >> 4) * 4 + rr;  // batch row
        float v = apply_act(acc[mt][nt][rr] + bv, aid);
        out[((size_t)b * TSTEPS + t) * OUTDIM + n] = v;
      }
    }
  }
}

__global__ __launch_bounds__(256) void cvt_bf16(
    const float* __restrict__ in, bf16* __restrict__ out, int n4) {
  int i = blockIdx.x * 256 + threadIdx.x;
  if (i < n4) {
    float4 v = ((const float4*)in)[i];
    union { bf16 b[4]; unsigned long long u; } pk;
    pk.b[0] = (bf16)v.x;
    pk.b[1] = (bf16)v.y;
    pk.b[2] = (bf16)v.z;
    pk.b[3] = (bf16)v.w;
    ((unsigned long long*)out)[i] = pk.u;
  }
}

__global__ __launch_bounds__(256) void zero32(uint32_t* __restrict__ p, int n) {
  int i = blockIdx.x * 256 + threadIdx.x;
  if (i < n) p[i] = 0u;
}

extern "C" void kernel_launch(void* const* d_in, const int* in_sizes, int n_in,
                              void* d_out, int out_size, void* d_ws, size_t ws_size,
                              hipStream_t stream) {
  const float* x     = (const float*)d_in[0];   // [64,128,512]
  const float* W_in  = (const float*)d_in[1];   // [2048,512]
  const float* b_in  = (const float*)d_in[2];   // [2048]
  const float* W_h   = (const float*)d_in[3];   // [4,2048,4096]
  const float* b_h   = (const float*)d_in[4];   // [4,2048]
  const float* W_out = (const float*)d_in[5];   // [256,2048]
  const float* b_out = (const float*)d_in[6];   // [256]
  const int* act_ids = (const int*)d_in[7];     // [5,2048]
  const int* out_act = (const int*)d_in[8];     // [256]
  float* out = (float*)d_out;                   // [64,128,256]

  char* w = (char*)d_ws;
  bf16* xbf   = (bf16*)w; w += (size_t)BATCH * TSTEPS * INDIM * 2;   // 8 MB
  bf16* winb  = (bf16*)w; w += (size_t)XDIM * INDIM * 2;             // 2 MB
  bf16* whb   = (bf16*)w; w += (size_t)4 * XDIM * (2 * XDIM) * 2;    // 64 MB
  bf16* woutb = (bf16*)w; w += (size_t)OUTDIM * XDIM * 2;            // 1 MB
  bf16* h0    = (bf16*)w; w += (size_t)TSTEPS * SLOTE * 2;           // 32 MB (doubles as h4 slots 2..)
  bf16* h1    = (bf16*)w; w += SLOTE * 2;
  bf16* h3    = (bf16*)w; w += SLOTE * 2;
  // ---- zero region ----
  char* zstart = w;
  bf16* extra = (bf16*)w; w += 2 * SLOTE * 2;   // h4 slots 0,1 (slot 0 must be 0)
  bf16* h2a   = (bf16*)w; w += SLOTE * 2;
  bf16* h2b   = (bf16*)w; w += SLOTE * 2;
  float* ss_li = (float*)w; w += (size_t)(TSTEPS + 1) * BATCH * 4;
  float* ss_bp = (float*)w; w += (size_t)(TSTEPS + 1) * BATCH * 4;
  int zero_u32 = (int)((w - zstart) / 4);

  cvt_bf16<<<4096, 256, 0, stream>>>(x, xbf, (BATCH * TSTEPS * INDIM) / 4);
  cvt_bf16<<<1024, 256, 0, stream>>>(W_in, winb, (XDIM * INDIM) / 4);
  cvt_bf16<<<32768, 256, 0, stream>>>(W_h, whb, (4 * XDIM * 2 * XDIM) / 4);
  cvt_bf16<<<512, 256, 0, stream>>>(W_out, woutb, (OUTDIM * XDIM) / 4);
  zero32<<<(zero_u32 + 255) / 256, 256, 0, stream>>>((uint32_t*)zstart, zero_u32);
  h0_gemm<<<dim3(16, 128), 256, 0, stream>>>(xbf, winb, b_in, act_ids, h0);

  // h4 slot s: s<2 -> extra[s], s>=2 -> h0 slice s-2 (dead after step s-2's
  // phase A; overwritten at step s-1's phase D -> safe, saves 32 MB).
  auto slotp = [&](int s) -> bf16* {
    return (s < 2) ? (extra + (size_t)s * SLOTE) : (h0 + (size_t)(s - 2) * SLOTE);
  };

  const size_t wstr = (size_t)XDIM * 2 * XDIM;
  for (int t = 0; t < TSTEPS; t++) {
    bf16* h2n = (t & 1) ? h2b : h2a;
    bf16* h2o = (t & 1) ? h2a : h2b;

    // h1 = act([h0_t, norm(h4_t)] @ W0^T + b0)
    step_gemm8<true, false><<<dim3(128, 2), 512, 0, stream>>>(
        h0 + (size_t)t * SLOTE, slotp(t), whb, b_h, act_ids + XDIM,
        ss_bp + t * BATCH, nullptr, h1);
    // h2 = act([h1, norm(h2_old)] @ W1^T + b1); emit ss_li[t+1]
    step_gemm8<true, true><<<dim3(128, 2), 512, 0, stream>>>(
        h1, h2o, whb + wstr, b_h + XDIM, act_ids + 2 * XDIM,
        ss_li + t * BATCH, ss_li + (t + 1) * BATCH, h2n);
    // h3 = act([h2, h1] @ W2^T + b2)
    step_gemm8<false, false><<<dim3(128, 2), 512, 0, stream>>>(
        h2n, h1, whb + 2 * wstr, b_h + 2 * XDIM, act_ids + 3 * XDIM,
        nullptr, nullptr, h3);
    // h4 = act([h3, h2] @ W3^T + b3) -> slot t+1; emit ss_bp[t+1]
    step_gemm8<false, true><<<dim3(128, 2), 512, 0, stream>>>(
        h3, h2n, whb + 3 * wstr, b_h + 3 * XDIM, act_ids + 4 * XDIM,
        nullptr, ss_bp + (t + 1) * BATCH, slotp(t + 1));
  }

  // all y_t in one GEMM over the stored h4 slots
  ybat_gemm<<<dim3(2, TSTEPS), 256, 0, stream>>>(
      extra, h0, woutb, b_out, out_act, out);
}